// Round 6
// baseline (990.225 us; speedup 1.0000x reference)
//
#include <hip/hip_runtime.h>
#include <math.h>

#define N_NODES 100000
#define N_EDGES 3200000
#define NODE_F  128
#define EDGE_F  16
#define OUT_C   15

#define SCAN_B    1024
#define SCAN_NBLK ((N_NODES + SCAN_B - 1) / SCAN_B)   // 98

// native clang vector: accepted by __builtin_nontemporal_load/store
// (HIP_vector_type float4 is NOT).
typedef float f32x4 __attribute__((ext_vector_type(4)));

// ---------------------------------------------------------------------------
// Kernel 1: xw = x @ W_node   ([N,128] @ [128,15] -> [N,15])
// One thread/node; W_node in LDS; per-lane float4 row reads.
// ---------------------------------------------------------------------------
__global__ __launch_bounds__(256) void node_proj_kernel(
    const float* __restrict__ x, const float* __restrict__ wn,
    float* __restrict__ xw)
{
    __shared__ float wl[NODE_F * OUT_C];  // 1920 floats
    const int tid = threadIdx.x;
    for (int i = tid; i < NODE_F * OUT_C; i += 256) wl[i] = wn[i];
    __syncthreads();

    const int n = blockIdx.x * 256 + tid;
    if (n >= N_NODES) return;

    float acc[OUT_C];
#pragma unroll
    for (int c = 0; c < OUT_C; ++c) acc[c] = 0.f;

    const f32x4* xr = (const f32x4*)(x + (size_t)n * NODE_F);
#pragma unroll 4
    for (int k4 = 0; k4 < NODE_F / 4; ++k4) {
        f32x4 v = xr[k4];
#pragma unroll
        for (int j = 0; j < 4; ++j) {
            const float xv = v[j];
            const int k = k4 * 4 + j;
#pragma unroll
            for (int c = 0; c < OUT_C; ++c)
                acc[c] = fmaf(xv, wl[k * OUT_C + c], acc[c]);
        }
    }

    float* out = xw + (size_t)n * OUT_C;
#pragma unroll
    for (int c = 0; c < OUT_C; ++c) out[c] = acc[c];
}

// ---------------------------------------------------------------------------
// Binning pipeline: histogram -> scan -> scatter bins -> gather
// Replaces 48M device-scope f32 atomics (R2: 297us, WRITE_SIZE 275MB for a
// 6MB target) with int atomics on a 400KB table + one clean write of axw.
// ---------------------------------------------------------------------------
__global__ __launch_bounds__(256) void hist_kernel(
    const int* __restrict__ rows, int* __restrict__ cnt)
{
    const int e = blockIdx.x * 256 + threadIdx.x;
    if (e < N_EDGES) atomicAdd(&cnt[rows[e]], 1);
}

__global__ __launch_bounds__(SCAN_B) void scan_a_kernel(
    const int* __restrict__ cnt, int* __restrict__ partials)
{
    __shared__ int s[SCAN_B];
    const int i = blockIdx.x * SCAN_B + threadIdx.x;
    s[threadIdx.x] = (i < N_NODES) ? cnt[i] : 0;
    __syncthreads();
    for (int st = SCAN_B / 2; st > 0; st >>= 1) {
        if (threadIdx.x < st) s[threadIdx.x] += s[threadIdx.x + st];
        __syncthreads();
    }
    if (threadIdx.x == 0) partials[blockIdx.x] = s[0];
}

__global__ void scan_b_kernel(const int* __restrict__ partials,
                              int* __restrict__ block_off, int* __restrict__ off)
{
    if (threadIdx.x == 0 && blockIdx.x == 0) {
        int acc = 0;
        for (int b = 0; b < SCAN_NBLK; ++b) { block_off[b] = acc; acc += partials[b]; }
        off[N_NODES] = acc;   // == N_EDGES
    }
}

__global__ __launch_bounds__(SCAN_B) void scan_c_kernel(
    const int* __restrict__ cnt, const int* __restrict__ block_off,
    int* __restrict__ off, int* __restrict__ cur)
{
    __shared__ int s[SCAN_B];
    const int i = blockIdx.x * SCAN_B + threadIdx.x;
    const int v = (i < N_NODES) ? cnt[i] : 0;
    s[threadIdx.x] = v;
    __syncthreads();
    for (int st = 1; st < SCAN_B; st <<= 1) {
        int t = (threadIdx.x >= st) ? s[threadIdx.x - st] : 0;
        __syncthreads();
        s[threadIdx.x] += t;
        __syncthreads();
    }
    if (i < N_NODES) {
        const int ex = block_off[blockIdx.x] + s[threadIdx.x] - v;  // exclusive
        off[i] = ex;
        cur[i] = ex;
    }
}

__global__ __launch_bounds__(256) void scatter_bins_kernel(
    const int* __restrict__ rows, const int* __restrict__ cols,
    const float* __restrict__ adj, int* __restrict__ cur,
    int2* __restrict__ bins)
{
    const int e = blockIdx.x * 256 + threadIdx.x;
    if (e >= N_EDGES) return;
    const int r   = __builtin_nontemporal_load(rows + e);
    const int c   = __builtin_nontemporal_load(cols + e);
    const float a = __builtin_nontemporal_load(adj + e);
    const int pos = atomicAdd(&cur[r], 1);
    bins[pos] = make_int2(c, __float_as_int(a));
}

// 16 lanes/node: lane c sums column c over the node's contiguous bin list.
// bins reads broadcast across the 16-lane group; xw gathers hit L2/L3.
__global__ __launch_bounds__(256) void gather_axw_kernel(
    const int* __restrict__ off, const int2* __restrict__ bins,
    const float* __restrict__ xw, float* __restrict__ axw)
{
    const int gid = blockIdx.x * 256 + threadIdx.x;
    const int n = gid >> 4;
    const int c = gid & 15;
    if (c >= OUT_C) return;
    const int start = off[n], end = off[n + 1];
    float acc = 0.f;
    for (int i = start; i < end; ++i) {
        const int2 b = bins[i];
        acc += __int_as_float(b.y) * xw[(size_t)b.x * OUT_C + c];
    }
    axw[(size_t)n * OUT_C + c] = acc;
}

// ---------------------------------------------------------------------------
// Fallback (ws too small): direct atomic scatter
// ---------------------------------------------------------------------------
__global__ __launch_bounds__(256) void edge_scatter_kernel(
    const int* __restrict__ rows, const int* __restrict__ cols,
    const float* __restrict__ adj, const float* __restrict__ xw,
    float* __restrict__ axw)
{
    const int gid = blockIdx.x * 256 + threadIdx.x;
    const int e = gid >> 4;
    const int c = gid & 15;
    if (c >= OUT_C) return;
    const int r  = rows[e];
    const int cl = cols[e];
    atomicAdd(&axw[(size_t)r * OUT_C + c], adj[e] * xw[(size_t)cl * OUT_C + c]);
}

// ---------------------------------------------------------------------------
// Kernel 3 (fused): ew = edge_attr @ W_edge ; score = sigmoid(<axw[r]*ew*axw[c]>)
// ew tile staged in LDS -> fully coalesced float4 stores of the 192MB stream.
// LDS write stride 15 floats: gcd(15,32)=1 -> distinct banks; 2 lanes/bank
// on wave64 is free (m136).
// ---------------------------------------------------------------------------
__global__ __launch_bounds__(256) void edge_fused_kernel(
    const int* __restrict__ rows, const int* __restrict__ cols,
    const float* __restrict__ ea, const float* __restrict__ we,
    const float* __restrict__ axw,
    float* __restrict__ ew_out, float* __restrict__ scores)
{
    __shared__ float ws[EDGE_F * OUT_C];      // 240 floats
    __shared__ float sew[256 * OUT_C];        // 3840 floats = 15 KB
    if (threadIdx.x < EDGE_F * OUT_C) ws[threadIdx.x] = we[threadIdx.x];
    __syncthreads();

    const int e = blockIdx.x * 256 + threadIdx.x;   // grid exact: E%256==0

    const f32x4* ear = (const f32x4*)(ea + (size_t)e * EDGE_F);
    float av[EDGE_F];
#pragma unroll
    for (int j = 0; j < 4; ++j) {
        f32x4 v = __builtin_nontemporal_load(ear + j);
        av[4 * j + 0] = v[0]; av[4 * j + 1] = v[1];
        av[4 * j + 2] = v[2]; av[4 * j + 3] = v[3];
    }

    float ew[OUT_C];
#pragma unroll
    for (int c = 0; c < OUT_C; ++c) ew[c] = 0.f;
#pragma unroll
    for (int k = 0; k < EDGE_F; ++k) {
        const float a = av[k];
#pragma unroll
        for (int c = 0; c < OUT_C; ++c)
            ew[c] = fmaf(a, ws[k * OUT_C + c], ew[c]);
    }

    // stage ew in LDS
#pragma unroll
    for (int c = 0; c < OUT_C; ++c)
        sew[threadIdx.x * OUT_C + c] = ew[c];

    // bilinear score while the LDS write settles
    const int r  = rows[e];
    const int cl = cols[e];
    const float* h = axw + (size_t)r  * OUT_C;
    const float* t = axw + (size_t)cl * OUT_C;
    float s = 0.f;
#pragma unroll
    for (int c = 0; c < OUT_C; ++c)
        s += ew[c] * h[c] * t[c];
    __builtin_nontemporal_store(1.f / (1.f + expf(-s)), scores + e);

    __syncthreads();

    // coalesced float4 flush of the block's ew tile (3840 floats = 960 f32x4)
    f32x4* dst4 = (f32x4*)(ew_out + (size_t)blockIdx.x * 256 * OUT_C);
    const f32x4* src4 = (const f32x4*)sew;
    for (int j = threadIdx.x; j < 256 * OUT_C / 4; j += 256)
        __builtin_nontemporal_store(src4[j], dst4 + j);
}

// ---------------------------------------------------------------------------
static inline size_t align256(size_t x) { return (x + 255) & ~(size_t)255; }

extern "C" void kernel_launch(void* const* d_in, const int* in_sizes, int n_in,
                              void* d_out, int out_size, void* d_ws, size_t ws_size,
                              hipStream_t stream) {
    const float* x    = (const float*)d_in[0];
    const int*   eidx = (const int*)d_in[1];     // [2,E]: rows then cols
    const float* ea   = (const float*)d_in[2];
    const float* wn   = (const float*)d_in[3];
    const float* we   = (const float*)d_in[4];
    const float* adj  = (const float*)d_in[5];

    const int* rows = eidx;
    const int* cols = eidx + N_EDGES;

    float* out    = (float*)d_out;
    float* axw    = out;                                      // [N,15]
    float* ew_out = out + (size_t)N_NODES * OUT_C;            // [E,15]
    float* scores = out + (size_t)N_NODES * OUT_C
                        + (size_t)N_EDGES * OUT_C;            // [E]

    // ws carve-up
    char* w = (char*)d_ws;
    float* xw = (float*)w;        w += align256((size_t)N_NODES * OUT_C * 4);
    int* cnt = (int*)w;           w += align256((size_t)N_NODES * 4);
    int* off = (int*)w;           w += align256((size_t)(N_NODES + 1) * 4);
    int* cur = (int*)w;           w += align256((size_t)N_NODES * 4);
    int* partials = (int*)w;      w += align256((size_t)SCAN_NBLK * 4);
    int* block_off = (int*)w;     w += align256((size_t)SCAN_NBLK * 4);
    int2* bins = (int2*)w;        w += (size_t)N_EDGES * sizeof(int2);
    const size_t ws_needed = (size_t)(w - (char*)d_ws);

    // 1) xw = x @ W_node
    node_proj_kernel<<<(N_NODES + 255) / 256, 256, 0, stream>>>(x, wn, xw);

    if (ws_size >= ws_needed) {
        // 2) bin edges by row (counting sort), then gather — no float atomics
        (void)hipMemsetAsync(cnt, 0, (size_t)N_NODES * 4, stream);
        hist_kernel<<<(N_EDGES + 255) / 256, 256, 0, stream>>>(rows, cnt);
        scan_a_kernel<<<SCAN_NBLK, SCAN_B, 0, stream>>>(cnt, partials);
        scan_b_kernel<<<1, 64, 0, stream>>>(partials, block_off, off);
        scan_c_kernel<<<SCAN_NBLK, SCAN_B, 0, stream>>>(cnt, block_off, off, cur);
        scatter_bins_kernel<<<(N_EDGES + 255) / 256, 256, 0, stream>>>(
            rows, cols, adj, cur, bins);
        gather_axw_kernel<<<(N_NODES * 16) / 256, 256, 0, stream>>>(
            off, bins, xw, axw);
    } else {
        // fallback: direct atomic scatter
        (void)hipMemsetAsync(axw, 0, (size_t)N_NODES * OUT_C * 4, stream);
        edge_scatter_kernel<<<(N_EDGES * 16) / 256, 256, 0, stream>>>(
            rows, cols, adj, xw, axw);
    }

    // 3) ew + scores (fused)
    edge_fused_kernel<<<N_EDGES / 256, 256, 0, stream>>>(
        rows, cols, ea, we, axw, ew_out, scores);
}